// Round 9
// baseline (91.482 us; speedup 1.0000x reference)
//
#include <hip/hip_runtime.h>
#include <hip/hip_bf16.h>
#include <math.h>

// Problem constants
#define B_     2
#define CIN    32
#define HH     512
#define WW     512
#define HID    768
#define SZ     16
#define NPATCH 1024      // 32x32 patch grid
#define KDIM   8192      // CIN*SZ*SZ
#define NCLS   21
#define LAT    128
#define LC     2688      // LAT*NCLS
#define NP     (B_ * NPATCH)   // 2048 patch rows

// prep-kernel block ranges (classlat FIRST: longest serial chain)
#define NB_CL  63        // NCLS*3 : classlat (cls, 256-wide d-segment), norms inline
#define NB_W4  1536      // HID*KDIM/16/256  (4 float4 per thread)

typedef __attribute__((ext_vector_type(8))) short short8;   // 8 bf16 (4 VGPR)
typedef __attribute__((ext_vector_type(4))) float f32x4;

// RNE float->bf16
__device__ __forceinline__ ushort f2bf(float f) {
    union { float f; unsigned u; } v; v.f = f;
    unsigned r = (v.u + 0x7fff + ((v.u >> 16) & 1)) >> 16;
    return (ushort)r;
}
__device__ __forceinline__ float bf2f(ushort u) {
    union { unsigned u; float f; } v; v.u = (unsigned)u << 16;
    return v.f;
}

__device__ __forceinline__ void gload16(const void* g, void* l) {
    __builtin_amdgcn_global_load_lds(
        (const __attribute__((address_space(1))) unsigned int*)g,
        (__attribute__((address_space(3))) unsigned int*)l, 16, 0, 0);
}

// pack 2 f32 -> 1 u32 of 2 bf16 (RNE); compiler emits v_cvt_pk (m240: don't hand-asm)
__device__ __forceinline__ unsigned pk2bf(float a, float b) {
    union { __hip_bfloat162 h; unsigned u; } cv;
    cv.h = __float22bfloat162_rn(make_float2(a, b));
    return cv.u;
}

// ---------------------------------------------------------------------------
// Prep kernel.  ROUND-9: x is NOT touched here at all — the GEMM stages f32 x
// directly (async gload_lds) and converts on the LDS-read side.  Prep is now
// only conv_w (50MB) + classlat (8.3MB): ~11us streaming.
//   blocks [0, NB_CL)    : classlat (norms inline, 3 d-segments per class)
//   blocks [.., +NB_W4)  : conv_w f32 -> bf16 (4-deep batch, dense both sides)
// ---------------------------------------------------------------------------
__global__ __launch_bounds__(256) void k_prep(const float* __restrict__ w,
                                              const float* __restrict__ lat,
                                              ushort* __restrict__ wb,
                                              float* __restrict__ classlat) {
    const int bid = blockIdx.x;
    const int t   = threadIdx.x;

    if (bid < NB_CL) {
        // ---- classlat with inline row norms ----
        const int cls  = bid / 3;
        const int dseg = bid % 3;
        const int lane = t & 63, wvv = t >> 6;
        __shared__ float sc_sh[LAT];

        for (int q = 0; q < 32; q += 2) {
            int u0 = wvv * 32 + q;
            const float* r0 = lat + (size_t)(u0 * NCLS + cls) * HID;
            const float* r1 = lat + (size_t)((u0 + 1) * NCLS + cls) * HID;
            float s0 = 0.f, s1 = 0.f;
#pragma unroll
            for (int e = 0; e < HID / 64; ++e) {
                float a = r0[lane + e * 64]; s0 += a * a;
                float b2 = r1[lane + e * 64]; s1 += b2 * b2;
            }
#pragma unroll
            for (int off = 32; off >= 1; off >>= 1) {
                s0 += __shfl_xor(s0, off, 64);
                s1 += __shfl_xor(s1, off, 64);
            }
            if (lane == 0) {
                sc_sh[u0]     = 1.0f / (128.0f * sqrtf(s0));
                sc_sh[u0 + 1] = 1.0f / (128.0f * sqrtf(s1));
            }
        }
        __syncthreads();

        const float* src = lat + (size_t)cls * HID + dseg * 256 + t;
        float a = 0.f;
        for (int u0 = 0; u0 < LAT; u0 += 8) {
            float v[8];
#pragma unroll
            for (int q = 0; q < 8; ++q)
                v[q] = src[(size_t)(u0 + q) * (NCLS * HID)];
#pragma unroll
            for (int q = 0; q < 8; ++q) a += v[q] * sc_sh[u0 + q];
        }
        classlat[cls * HID + dseg * 256 + t] = a;
    } else {
        // ---- conv_w convert (coalesced both sides, 4 loads in flight) ----
        const int cb = bid - NB_CL;
        float4 vv[4];
#pragma unroll
        for (int k = 0; k < 4; ++k)
            vv[k] = *(const float4*)(w + ((size_t)cb * 1024 + k * 256 + t) * 4);
#pragma unroll
        for (int k = 0; k < 4; ++k) {
            ushort4 o;
            o.x = f2bf(vv[k].x); o.y = f2bf(vv[k].y);
            o.z = f2bf(vv[k].z); o.w = f2bf(vv[k].w);
            *(ushort4*)(wb + ((size_t)cb * 1024 + k * 256 + t) * 4) = o;
        }
    }
}

// ---------------------------------------------------------------------------
// MFMA GEMM, ROUND-9: reads f32 x DIRECTLY (no xb buffer anywhere).
// patch[p][d] = sum_k x-as-A[p][k] * wb[d][k],  k = c*256 + i*16 + j.
// 256x128 tile, BK=32, 8 waves (4x2), wave 64x64 via 4x4 mfma 16x16x32 bf16.
// 2-PHASE double-buffered pipeline (T3-minimum, §5.5): STAGE(t+1) issued
// before COMPUTE(t); the single __syncthreads() per K-step drains vmcnt
// (t+1 landed) and guards the buffer swap.  Loads hide under 16 MFMAs.
// A: f32 LDS tile [256][32] (32KB/buf).  Per-lane gather source (round-8
//    proven mechanism): chunk (row r, slot e) <- logical chunk e^(r&7)
//    = x[(bxb,c, ph(r)*16 + i0 + (esrc>>2), pw(r)*16 + (esrc&3)*4 ..+3]].
//    Wave's 64 chunks = two contiguous 512B segments (coalesced).
//    Read side: stored chunks (2fq)^(fr&7), (2fq+1)^(fr&7) -> 8-way-min
//    banks; cvt_pk f32->bf16 during fragment build (4/frag).
// B: bf16 wb, [128][32] LDS (8KB/buf), UNswizzled (row stride 16 dwords is
//    already bank-minimal for both the linear gload_lds fill and fq*8 reads).
// T1 bijective XCD remap unchanged; A panel/bx = 2MB f32 -> L2-resident
// across the 6 by re-reads.  Output layout: pbuf[p][z][d] (unchanged).
// ---------------------------------------------------------------------------
template <int SPLITK>
__global__ __launch_bounds__(512, 4) void k_gemm(const float* __restrict__ x,
                                                 const ushort* __restrict__ wb,
                                                 ushort* __restrict__ pbuf) {
    constexpr int KS = KDIM / SPLITK;
    constexpr int NT = KS / 32;        // K-steps of 32
    __shared__ float  Af[2][256 * 32];   // 2 x 32 KB
    __shared__ ushort Bf[2][128 * 32];   // 2 x 8 KB   (total 80 KB -> 2 blk/CU)

    // ---- T1 remap: grid (8, 6, SPLITK), nwg = 48*SPLITK (always %8==0) ----
    const int flat = blockIdx.x + 8 * (blockIdx.y + 6 * blockIdx.z);
    constexpr int nwg = 48 * SPLITK;
    const int wg = (flat & 7) * (nwg >> 3) + (flat >> 3);
    const int bz = wg / 48;
    const int rr = wg - bz * 48;
    const int by = rr % 6;       // by-fastest: consecutive blocks share the A panel
    const int bx = rr / 6;

    const int tid  = threadIdx.x;
    const int wv   = tid >> 6;         // 0..7
    const int lane = tid & 63;
    const int wm   = (wv >> 1) * 64;   // wave row offset (0..192)
    const int wn   = (wv & 1) * 64;    // wave col offset (0/64)

    const int bxb = bx >> 2;           // batch index
    const int ph0 = (bx & 3) * 8;      // first ph of this tile

    // ---- A gather: lane-invariant offset (f32 elems) ----
    // chunk n = q*512 + tid :  r = n>>3 (tile row), e = n&7 (16B slot)
    // esrc = e ^ (r&7) [store-side XOR];  r&7 = (tid>>3)&7 (q*64 = 0 mod 8)
    const int esrc = (tid & 7) ^ ((tid >> 3) & 7);
    const size_t alane = (size_t)(tid >> 8) * 8192        // ph += tid>>8
                       + (size_t)(esrc >> 2) * 512        // i   = i0 + (esrc>>2)
                       + (size_t)((tid >> 3) & 31) * 16   // pw*16
                       + (size_t)(esrc & 3) * 4;          // j quad
    const float* xA0 = x + (size_t)bxb * 8388608 + (size_t)ph0 * 8192 + alane;

    // ---- B gather: linear (no swizzle needed at BK=32) ----
    const ushort* wB0 = wb + (size_t)(by * 128 + (tid >> 2)) * KDIM
                      + (size_t)bz * KS + (tid & 3) * 8;

    f32x4 acc[4][4];
#pragma unroll
    for (int m = 0; m < 4; ++m)
#pragma unroll
        for (int n = 0; n < 4; ++n) acc[m][n] = (f32x4)(0.f);

    const int fr = lane & 15, fq = lane >> 4;
    const int frk = fr & 7;

    auto STAGE = [&](int ks, int bsel) {
        const int gkg = bz * KS + ks * 32;
        const int c   = gkg >> 8;
        const int i0  = (gkg >> 4) & 15;
        const float* xs = xA0 + (size_t)c * 262144 + (size_t)i0 * 512;
#pragma unroll
        for (int q = 0; q < 4; ++q)                    // q advances ph by 2
            gload16(xs + (size_t)q * 16384, &Af[bsel][q * 2048 + wv * 256]);
        gload16(wB0 + ks * 32, &Bf[bsel][tid * 8]);
    };

    auto COMPUTE = [&](int bsel) {
        const float*  Ac = Af[bsel];
        const ushort* Bc = Bf[bsel];
        short8 af[4], bf[4];
#pragma unroll
        for (int m = 0; m < 4; ++m) {
            const int row = (wm + m * 16 + fr) * 32;
            const int c0  = (((2 * fq)     ^ frk) * 4);
            const int c1  = (((2 * fq + 1) ^ frk) * 4);
            f32x4 lo = *(const f32x4*)&Ac[row + c0];   // logical k fq*8..+3
            f32x4 hi = *(const f32x4*)&Ac[row + c1];   // logical k fq*8+4..+7
            union { unsigned u[4]; short8 s; } cv;
            cv.u[0] = pk2bf(lo[0], lo[1]);
            cv.u[1] = pk2bf(lo[2], lo[3]);
            cv.u[2] = pk2bf(hi[0], hi[1]);
            cv.u[3] = pk2bf(hi[2], hi[3]);
            af[m] = cv.s;
        }
#pragma unroll
        for (int n = 0; n < 4; ++n)
            bf[n] = *(const short8*)&Bc[(wn + n * 16 + fr) * 32 + fq * 8];
#pragma unroll
        for (int m = 0; m < 4; ++m)
#pragma unroll
            for (int n = 0; n < 4; ++n)
                acc[m][n] = __builtin_amdgcn_mfma_f32_16x16x32_bf16(af[m], bf[n], acc[m][n], 0, 0, 0);
    };

    // ---- 2-phase pipeline ----
    STAGE(0, 0);
    __syncthreads();                       // buf0 ready (barrier drains vmcnt)
    for (int ks = 0; ks < NT; ++ks) {
        if (ks + 1 < NT) STAGE(ks + 1, (ks + 1) & 1);   // in flight during compute
        COMPUTE(ks & 1);
        __syncthreads();                   // t+1 landed; all waves done with buf
    }

#pragma unroll
    for (int m = 0; m < 4; ++m) {
#pragma unroll
        for (int n = 0; n < 4; ++n) {
            int col = by * 128 + wn + n * 16 + fr;
#pragma unroll
            for (int j = 0; j < 4; ++j) {
                int row = bx * 256 + wm + m * 16 + fq * 4 + j;
                pbuf[((size_t)row * SPLITK + bz) * HID + col] = f2bf(acc[m][n][j]);
            }
        }
    }
}

// ---------------------------------------------------------------------------
// Per-patch epilogue: stage the patch's contiguous [SPLITK][HID] bf16 partials
// into LDS (coalesced 16B loads), sum + bias -> norm -> 21 dots ->
// masked exp(2*sim) -> partial[p].
// ---------------------------------------------------------------------------
template <int SPLITK>
__global__ __launch_bounds__(256) void k_final(const ushort* __restrict__ pbuf,
                                               const float* __restrict__ conv_b,
                                               const float* __restrict__ classlat,
                                               const int* __restrict__ mask,
                                               float* __restrict__ partial) {
    const int p = blockIdx.x;        // 0..2047
    const int b = p >> 10, n = p & 1023;
    const int t = threadIdx.x;
    const int lane = t & 63, wv = t >> 6;

    __shared__ ushort sh[SPLITK * HID];
    const ushort* pb = pbuf + (size_t)p * (SPLITK * HID);
    for (int i = t; i < SPLITK * HID / 8; i += 256)
        *(short8*)&sh[i * 8] = *(const short8*)&pb[(size_t)i * 8];
    __syncthreads();

    float f0 = conv_b[t], f1 = conv_b[t + 256], f2 = conv_b[t + 512];
#pragma unroll
    for (int z = 0; z < SPLITK; ++z) {
        f0 += bf2f(sh[z * HID + t]);
        f1 += bf2f(sh[z * HID + t + 256]);
        f2 += bf2f(sh[z * HID + t + 512]);
    }

    __shared__ float wsum[4];
    __shared__ float wdot[4][NCLS];
    __shared__ float cpart[NCLS];

    float ss = f0 * f0 + f1 * f1 + f2 * f2;
#pragma unroll
    for (int off = 32; off >= 1; off >>= 1) ss += __shfl_xor(ss, off, 64);
    if (lane == 0) wsum[wv] = ss;

    float dots[NCLS];
#pragma unroll
    for (int c = 0; c < NCLS; ++c) {
        const float* cl = classlat + c * HID;
        dots[c] = cl[t] * f0 + cl[t + 256] * f1 + cl[t + 512] * f2;
    }
#pragma unroll
    for (int c = 0; c < NCLS; ++c) {
        float v = dots[c];
#pragma unroll
        for (int off = 32; off >= 1; off >>= 1) v += __shfl_xor(v, off, 64);
        if (lane == 0) wdot[wv][c] = v;
    }
    __syncthreads();

    if (t < NCLS) {
        float tot  = wsum[0] + wsum[1] + wsum[2] + wsum[3];
        float invn = 1.0f / sqrtf(tot);
        float dot  = wdot[0][t] + wdot[1][t] + wdot[2][t] + wdot[3][t];
        float sim  = dot * invn;
        int   mv   = mask[(size_t)(b * NCLS + t) * NPATCH + n];
        cpart[t]   = (mv != 0) ? expf(sim * 2.0f) : 0.0f;
    }
    __syncthreads();
    if (t == 0) {
        float s = 0.f;
#pragma unroll
        for (int c = 0; c < NCLS; ++c) s += cpart[c];
        partial[p] = s;
    }
}

__global__ __launch_bounds__(256) void k_reduce(const float* __restrict__ partial,
                                                float* __restrict__ out) {
    int t = threadIdx.x;
    float s = 0.f;
    for (int i = t; i < NP; i += 256) s += partial[i];
#pragma unroll
    for (int off = 32; off >= 1; off >>= 1) s += __shfl_xor(s, off, 64);
    __shared__ float ws[4];
    if ((t & 63) == 0) ws[t >> 6] = s;
    __syncthreads();
    if (t == 0) out[0] = -logf(ws[0] + ws[1] + ws[2] + ws[3]);
}

// ---------------------------------------------------------------------------
extern "C" void kernel_launch(void* const* d_in, const int* in_sizes, int n_in,
                              void* d_out, int out_size, void* d_ws, size_t ws_size,
                              hipStream_t stream) {
    const float* x      = (const float*)d_in[0];
    const int*   mask   = (const int*)d_in[1];
    const float* conv_w = (const float*)d_in[2];
    const float* conv_b = (const float*)d_in[3];
    const float* latent = (const float*)d_in[4];
    float* out = (float*)d_out;

    // workspace layout (bytes) — x is read directly by k_gemm; no xb buffer
    const size_t wb_bytes   = (size_t)HID * KDIM * 2;          // 12,582,912
    const size_t pslice     = (size_t)NP * HID * 2;            // 3,145,728 (bf16)
    const size_t small_need = (size_t)NCLS * HID * 4 + NP * 4 + 256;

    char* base = (char*)d_ws;
    ushort* wb   = (ushort*)base;
    ushort* pbuf = (ushort*)(base + wb_bytes);

    int splitk = 1;
    const size_t fixed = wb_bytes + small_need;
    if (ws_size >= fixed + 8 * pslice)      splitk = 8;
    else if (ws_size >= fixed + 4 * pslice) splitk = 4;
    else if (ws_size >= fixed + 2 * pslice) splitk = 2;

    float* classlat = (float*)(base + wb_bytes + (size_t)splitk * pslice);
    float* partial  = classlat + NCLS * HID;

    k_prep<<<NB_CL + NB_W4, 256, 0, stream>>>(conv_w, latent, wb, classlat);

    dim3 g(NP / 256, HID / 128, splitk);
    switch (splitk) {
        case 8: k_gemm<8><<<g, 512, 0, stream>>>(x, wb, pbuf); break;
        case 4: k_gemm<4><<<g, 512, 0, stream>>>(x, wb, pbuf); break;
        case 2: k_gemm<2><<<g, 512, 0, stream>>>(x, wb, pbuf); break;
        default: k_gemm<1><<<g, 512, 0, stream>>>(x, wb, pbuf); break;
    }

    switch (splitk) {
        case 8: k_final<8><<<NP, 256, 0, stream>>>(pbuf, conv_b, classlat, mask, partial); break;
        case 4: k_final<4><<<NP, 256, 0, stream>>>(pbuf, conv_b, classlat, mask, partial); break;
        case 2: k_final<2><<<NP, 256, 0, stream>>>(pbuf, conv_b, classlat, mask, partial); break;
        default: k_final<1><<<NP, 256, 0, stream>>>(pbuf, conv_b, classlat, mask, partial); break;
    }
    k_reduce<<<1, 256, 0, stream>>>(partial, out);
}